// Round 9
// baseline (240.280 us; speedup 1.0000x reference)
//
#include <hip/hip_runtime.h>

#define B_  4
#define S_  2048
#define D_  1024
#define H_  16
#define DH_ 64
#define M_  (B_ * S_)   // 8192 rows

typedef __attribute__((ext_vector_type(8))) short short8;
typedef __attribute__((ext_vector_type(4))) float floatx4;

// ---------- bf16 helpers ----------
__device__ __forceinline__ unsigned short f2bf(float f) {
    union { float f; unsigned int i; } v; v.f = f;
    unsigned int r = v.i + 0x7fffu + ((v.i >> 16) & 1u);   // RNE
    return (unsigned short)(r >> 16);
}
// truncation pack: two fp32 -> packed bf16x2 (P-weight trunc noise ~3e-5,
// harness-verified). Single v_perm_b32.
__device__ __forceinline__ unsigned int pk_trunc(float a, float b) {
#if __has_builtin(__builtin_amdgcn_perm)
    return __builtin_amdgcn_perm(__float_as_uint(b), __float_as_uint(a), 0x07060302u);
#else
    return (__float_as_uint(a) >> 16) | (__float_as_uint(b) & 0xffff0000u);
#endif
}

// raw 2^x (v_exp_f32). Q pre-scaled by 0.125*log2(e) in the GEMM epilogue.
#if __has_builtin(__builtin_amdgcn_exp2f)
#define EXP2(x) __builtin_amdgcn_exp2f(x)
#else
#define EXP2(x) __expf(0.6931471805599453f * (x))
#endif

// ---------- async global->LDS, 16B per lane ----------
typedef const __attribute__((address_space(1))) unsigned int* gas_ptr;
typedef __attribute__((address_space(3))) unsigned int* las_ptr;
__device__ __forceinline__ void async_cp16(const void* g, void* l) {
    __builtin_amdgcn_global_load_lds((gas_ptr)g, (las_ptr)l, 16, 0, 0);
}

#define VMC4 asm volatile("s_waitcnt vmcnt(4)" ::: "memory")
#define VMC0 asm volatile("s_waitcnt vmcnt(0)" ::: "memory")

// ---------- fused prep: x cast (blocks 0..8191) + W cast-transpose (8192..8959) ----------
__global__ __launch_bounds__(256) void cast_fused_kernel(
    const float* __restrict__ x, unsigned short* __restrict__ Ax,
    const float* __restrict__ W0, const float* __restrict__ W1,
    const float* __restrict__ W2,
    unsigned short* __restrict__ T0, unsigned short* __restrict__ T1,
    unsigned short* __restrict__ T2)
{
    const int bid = blockIdx.x;
    const int t = threadIdx.x;
    if (bid < 8192) {
        int i4 = bid * 256 + t;
        float4 v = reinterpret_cast<const float4*>(x)[i4];
        ushort4 o;
        o.x = f2bf(v.x); o.y = f2bf(v.y); o.z = f2bf(v.z); o.w = f2bf(v.w);
        reinterpret_cast<ushort4*>(Ax)[i4] = o;
        return;
    }
    const int idx = bid - 8192;               // 0..767
    const int z   = idx >> 8;                 // 0..2
    const int rem = idx & 255;
    const float* W = z == 0 ? W0 : (z == 1 ? W1 : W2);
    unsigned short* Wt = z == 0 ? T0 : (z == 1 ? T1 : T2);

    __shared__ unsigned short T[64][72];
    const int k0 = (rem & 15) * 64, n0 = (rem >> 4) * 64;

    #pragma unroll
    for (int p = 0; p < 4; ++p) {
        int kr = p * 16 + (t >> 4);
        int nc = (t & 15) * 4;
        float4 v = *reinterpret_cast<const float4*>(W + (size_t)(k0 + kr) * D_ + n0 + nc);
        T[nc + 0][kr] = f2bf(v.x);
        T[nc + 1][kr] = f2bf(v.y);
        T[nc + 2][kr] = f2bf(v.z);
        T[nc + 3][kr] = f2bf(v.w);
    }
    __syncthreads();

    const int nl = t >> 2, kc = (t & 3) * 16;
    size_t base = (size_t)(n0 + nl) * D_ + k0 + kc;
    *reinterpret_cast<short8*>(Wt + base)     = *reinterpret_cast<const short8*>(&T[nl][kc]);
    *reinterpret_cast<short8*>(Wt + base + 8) = *reinterpret_cast<const short8*>(&T[nl][kc + 8]);
}

// ---------- fused QKV GEMM v2: BM=BN=128, 256 thr, 64KB LDS, 2 blocks/CU ----------
// R8 counters: gemm 71.5us, MfmaUtil 28, VALU 16, occupancy 18% (1 block/CU,
// 96KB LDS). Per-phase floors: MFMA ~156cy/SIMD, ds_read ~192, L2-fetch ~183
// -- yet wall ~1786cy/phase: barrier rendezvous + vmcnt latency bubbles that
// one barrier domain per CU can't fill. v2: halve the block (BN 256->128,
// 512->256 threads, 4 waves), LDS 96->64KB -> TWO blocks/CU; grid 64x24 =
// 1536 = exactly 3 rounds of 512 slots. Phase thickness preserved (af[4] x
// bfr[4] = 16 MFMA/phase); same slot-XOR layout + fb read (validated 0-
// conflict); same 4-phase counted-vmcnt schedule with 4 cp16/thread per
// half-tile -> vmcnt(4) at P2/P4 (prologue 12 issues / VMC4; each wait lands
// exactly the two half-tiles the next two phases read -- re-derived).
// When block A stalls at a barrier/vmcnt, block B's waves issue MFMA.
// Per-XCD: ~2 B-panels (512KB) L2-resident; A streams from L3 (~14 TB/s agg,
// under the 34.5 TB/s L2 ceiling; gload_lds is latency-tolerant, unlike
// R5's latency-critical register loads).
__global__ __launch_bounds__(256, 2) void gemm_qkv_mfma(
    const unsigned short* __restrict__ Ax,
    const unsigned short* __restrict__ Wt,    // [3072][1024] = Q,K,V weights^T
    const float* __restrict__ bq, const float* __restrict__ bk,
    const float* __restrict__ bv,
    unsigned short* __restrict__ Q,           // Q,K contiguous (K = Q + M_*D_)
    unsigned short* __restrict__ Vtg)
{
    __shared__ unsigned short lds[32768];     // 64 KB

    const int tid  = threadIdx.x;             // 0..255
    const int lane = tid & 63;
    const int w    = tid >> 6;                // 0..3
    const int wm   = w >> 1;                  // 0..1  (64-row half of BM=128)
    const int wn   = w & 1;                   // 0..1  (64-col half of BN=128)
    const int l15  = lane & 15, quad = lane >> 4;

    // stage constants: lane-linear LDS dest, slot-XOR applied to global source
    const int pl   = tid >> 3;                // 0..31 (super-row of first sub-sweep)
    const int sl   = tid & 7;
    const int xx   = sl ^ (pl & 7);
    const int sro  = pl * 2 + (xx >> 2);      // logical row 0..63 in sub-sweep
    const int sc   = (xx & 3) * 8;            // k-chunk (shorts)
    // fragment-read offset (same XOR)
    const int fb = (l15 >> 1) * 64 + ((((l15 & 1) << 2) | quad) ^ (l15 >> 1)) * 8;

    const int id  = blockIdx.x;
    const int g   = (id & 7) * 192 + (id >> 3);   // 1536 = 8 XCD x 192, bijective
    const int nb  = g >> 6;                   // 0..23
    const int mb  = g & 63;                   // 0..63
    const int m0  = mb * 128;
    const int n0g = nb * 128;                 // global col in [0,3072)
    const int mat = nb >> 3;
    const int n0m = (nb & 7) * 128;           // col within its matrix
    const float* bias = mat == 0 ? bq : (mat == 1 ? bk : bv);

    // half-tile regions (shorts): buf0 A.h0=0 A.h1=4096 B.h0=8192 B.h1=12288;
    // buf1 = +16384. STGH stages one K-half of A (rA) and B (rA+8192):
    // 2 sub-sweeps of 64 rows each => 4 cp16/thread.
    #define STGH(kcol, rA) do { \
        async_cp16(Ax + (size_t)(m0 + sro) * 1024 + (kcol) + sc,        lds + (rA) + tid * 8); \
        async_cp16(Ax + (size_t)(m0 + 64 + sro) * 1024 + (kcol) + sc,   lds + (rA) + 2048 + tid * 8); \
        async_cp16(Wt + (size_t)(n0g + sro) * 1024 + (kcol) + sc,       lds + (rA) + 8192 + tid * 8); \
        async_cp16(Wt + (size_t)(n0g + 64 + sro) * 1024 + (kcol) + sc,  lds + (rA) + 10240 + tid * 8); \
    } while (0)

    floatx4 acc[4][4] = {};

    // prologue: tile0 both halves + tile1 h0 (12 cp16); keep tile1.h0 in flight
    STGH(0, 0);
    STGH(32, 4096);
    STGH(64, 16384);
    VMC4;
    __builtin_amdgcn_s_barrier();

    #define PH(bufS, ksub, STAGE_STMT, WAIT_STMT) do { \
        short8 af[4], bfr[4]; \
        _Pragma("unroll") \
        for (int i = 0; i < 4; ++i) \
            af[i] = *reinterpret_cast<const short8*>(lds + (bufS) + (ksub) * 4096 + wm * 2048 + i * 512 + fb); \
        _Pragma("unroll") \
        for (int j = 0; j < 4; ++j) \
            bfr[j] = *reinterpret_cast<const short8*>(lds + (bufS) + 8192 + (ksub) * 4096 + wn * 2048 + j * 512 + fb); \
        STAGE_STMT; \
        __builtin_amdgcn_s_barrier(); \
        asm volatile("s_waitcnt lgkmcnt(0)" ::: "memory"); \
        __builtin_amdgcn_sched_barrier(0); \
        __builtin_amdgcn_s_setprio(1); \
        _Pragma("unroll") \
        for (int i = 0; i < 4; ++i) \
            _Pragma("unroll") \
            for (int j = 0; j < 4; ++j) \
                acc[i][j] = __builtin_amdgcn_mfma_f32_16x16x32_bf16(af[i], bfr[j], acc[i][j], 0, 0, 0); \
        __builtin_amdgcn_s_setprio(0); \
        WAIT_STMT; \
        __builtin_amdgcn_s_barrier(); \
    } while (0)

    #pragma unroll 1
    for (int it = 0; it < 8; ++it) {
        const bool nl = (it < 7);
        const int  kA = (2 * it + 1) * 64;    // odd tile k-col
        const int  kB = kA + 64;
        const int  kC = kA + 128;
        PH(0,     0, STGH(kA + 32, 20480), );
        PH(0,     1, if (nl) STGH(kB, 0), { if (nl) VMC4; else VMC0; });
        PH(16384, 0, if (nl) STGH(kB + 32, 4096), );
        PH(16384, 1, if (nl) STGH(kC, 16384), { if (nl) VMC4; });
    }

    float bb[4];
    #pragma unroll
    for (int j = 0; j < 4; ++j) bb[j] = bias[n0m + wn * 64 + j * 16 + l15];

    if (mat == 2) {
        const int bI = m0 >> 11;
        #pragma unroll
        for (int i = 0; i < 4; ++i) {
            int srow = (m0 & 2047) + wm * 64 + i * 16 + quad * 4;
            #pragma unroll
            for (int j = 0; j < 4; ++j) {
                int col = n0m + wn * 64 + j * 16 + l15;
                ushort4 o;
                o.x = f2bf(acc[i][j][0] + bb[j]);
                o.y = f2bf(acc[i][j][1] + bb[j]);
                o.z = f2bf(acc[i][j][2] + bb[j]);
                o.w = f2bf(acc[i][j][3] + bb[j]);
                *reinterpret_cast<ushort4*>(Vtg + (size_t)(bI * 1024 + col) * S_ + srow) = o;
            }
        }
    } else {
        unsigned short* C = Q + (size_t)mat * M_ * D_;
        // Q scale folds softmax 1/sqrt(64) AND exp->exp2 log2(e)
        const float scq = (mat == 0) ? 0.18033688011112042f : 1.0f;
        #pragma unroll
        for (int i = 0; i < 4; ++i)
            #pragma unroll
            for (int r = 0; r < 4; ++r) {
                int row = m0 + wm * 64 + i * 16 + quad * 4 + r;
                #pragma unroll
                for (int j = 0; j < 4; ++j)
                    C[(size_t)row * D_ + n0m + wn * 64 + j * 16 + l15] = f2bf((acc[i][j][r] + bb[j]) * scq);
            }
    }
}

// ---------- MFMA flash attention v10 (R8): conflict-free XOR LDS, kept ----------
// R8 verified: SQ_LDS_BANK_CONFLICT 8.39M -> 0, 71.1us, MfmaUtil 46 + VALU 43
// ~= 89% dual-pipe issue -- structural plateau for this shape.
#define KT_   64
#define NT_   (S_ / KT_)
// logical (row, col in shorts) -> physical short index, conflict-free involution
#define SWZ(row, col) ((((row) << 6)) + ((col) ^ (((row) & 7) << 3)))

__global__ __launch_bounds__(256, 4) void attn_mfma(
    const unsigned short* __restrict__ Qg,
    const unsigned short* __restrict__ Kg,
    const unsigned short* __restrict__ Vtg,   // [(b*16+h)*64+d][s]
    float* __restrict__ out)
{
    __shared__ unsigned short Ks[KT_ * 64];      // [key][d], XOR-swizzled
    __shared__ unsigned short Vt[DH_ * 64];      // [d][k'], key-permuted + XOR-swizzled

    const int tid  = threadIdx.x;
    const int wq   = tid >> 6;
    const int lane = tid & 63;
    const int l15  = lane & 15;
    const int quad = lane >> 4;

    // XCD swizzle: 1024 = 8 xcd x 8 bh x 16 qt; per-XCD K/V footprint 4MB = L2
    const int id  = blockIdx.x;
    const int bh  = (id & 7) * 8 + ((id >> 3) & 7);
    const int qt  = id >> 6;                  // 0..15
    const int b   = bh >> 4;
    const int colbase = (bh & 15) * DH_;
    const int rowQ0 = b * S_ + qt * 128;

    short8 qf[2][2];
    #pragma unroll
    for (int g = 0; g < 2; ++g) {
        int qrow = rowQ0 + wq * 32 + g * 16 + l15;
        qf[g][0] = *reinterpret_cast<const short8*>(Qg + (size_t)qrow * D_ + colbase + quad * 8);
        qf[g][1] = *reinterpret_cast<const short8*>(Qg + (size_t)qrow * D_ + colbase + 32 + quad * 8);
    }

    // all-ones bf16 B-fragment for the denominator MFMA
    short8 vones;
    #pragma unroll
    for (int i = 0; i < 8; ++i) vones[i] = (short)0x3F80;

    floatx4 Oacc[2][4] = {};
    floatx4 Lacc[2] = {};

    // staging: thread covers rows p*32+srow, 16B key-chunk sc8
    const int srow = tid >> 3;        // 0..31
    const int sc8  = (tid & 7) * 8;
    const int vc  = sc8 >> 4;
    const int vqk = (sc8 >> 2) & 3;   // 0 or 2
    const int vk0 = ((vc & 1) << 2) + ((vc >> 1) << 5) + (vqk << 3);

    const unsigned short* Kbase = Kg + (size_t)(b * S_) * D_ + colbase;
    const unsigned short* Vbase = Vtg + (size_t)(bh * 64) * S_;

    short8 kpre[2], vpre[2];
    #pragma unroll
    for (int p = 0; p < 2; ++p) {
        kpre[p] = *reinterpret_cast<const short8*>(Kbase + (size_t)(p * 32 + srow) * D_ + sc8);
        vpre[p] = *reinterpret_cast<const short8*>(Vbase + (size_t)(p * 32 + srow) * S_ + sc8);
    }

    for (int kt = 0; kt < NT_; ++kt) {
        __syncthreads();
        #pragma unroll
        for (int p = 0; p < 2; ++p) {
            int r = p * 32 + srow;
            *reinterpret_cast<short8*>(&Ks[SWZ(r, sc8)]) = kpre[p];
            uint4 u = __builtin_bit_cast(uint4, vpre[p]);
            uint2 lo, hi;
            lo.x = u.x; lo.y = u.y; hi.x = u.z; hi.y = u.w;
            *reinterpret_cast<uint2*>(&Vt[SWZ(r, vk0)])     = lo;
            *reinterpret_cast<uint2*>(&Vt[SWZ(r, vk0 + 8)]) = hi;
        }
        __syncthreads();
        // issue-early: next tile's global loads AFTER the publish barrier
        if (kt + 1 < NT_) {
            int off = (kt + 1) * KT_;
            #pragma unroll
            for (int p = 0; p < 2; ++p) {
                kpre[p] = *reinterpret_cast<const short8*>(Kbase + (size_t)(off + p * 32 + srow) * D_ + sc8);
                vpre[p] = *reinterpret_cast<const short8*>(Vbase + (size_t)(p * 32 + srow) * S_ + off + sc8);
            }
        }

        // process 32 keys (= one PV MFMA's K) per half
        #pragma unroll
        for (int half = 0; half < 2; ++half) {
            floatx4 s_[2][2];
            __builtin_amdgcn_s_setprio(1);
            #pragma unroll
            for (int ci = 0; ci < 2; ++ci) {
                int c = half * 2 + ci;
                int kr = c * 16 + l15;
                short8 kf0 = *reinterpret_cast<const short8*>(&Ks[SWZ(kr, quad * 8)]);
                short8 kf1 = *reinterpret_cast<const short8*>(&Ks[SWZ(kr, 32 + quad * 8)]);
                #pragma unroll
                for (int g = 0; g < 2; ++g) {
                    floatx4 a = {0.f, 0.f, 0.f, 0.f};
                    a = __builtin_amdgcn_mfma_f32_16x16x32_bf16(kf0, qf[g][0], a, 0, 0, 0);
                    a = __builtin_amdgcn_mfma_f32_16x16x32_bf16(kf1, qf[g][1], a, 0, 0, 0);
                    s_[g][ci] = a;
                }
            }
            __builtin_amdgcn_s_setprio(0);
            // exp2 + pack directly into the K=32 A-fragment (k' order)
            short8 pa[2];
            #pragma unroll
            for (int g = 0; g < 2; ++g) {
                float p00 = EXP2(s_[g][0][0]), p01 = EXP2(s_[g][0][1]);
                float p02 = EXP2(s_[g][0][2]), p03 = EXP2(s_[g][0][3]);
                float p10 = EXP2(s_[g][1][0]), p11 = EXP2(s_[g][1][1]);
                float p12 = EXP2(s_[g][1][2]), p13 = EXP2(s_[g][1][3]);
                uint4 pu;
                pu.x = pk_trunc(p00, p01);
                pu.y = pk_trunc(p02, p03);
                pu.z = pk_trunc(p10, p11);
                pu.w = pk_trunc(p12, p13);
                pa[g] = __builtin_bit_cast(short8, pu);
            }
            // denominator + PV on the matrix pipe
            __builtin_amdgcn_s_setprio(1);
            #pragma unroll
            for (int g = 0; g < 2; ++g)
                Lacc[g] = __builtin_amdgcn_mfma_f32_16x16x32_bf16(pa[g], vones, Lacc[g], 0, 0, 0);
            #pragma unroll
            for (int d = 0; d < 4; ++d) {
                int vr = d * 16 + l15;
                short8 vf = *reinterpret_cast<const short8*>(&Vt[SWZ(vr, half * 32 + quad * 8)]);
                #pragma unroll
                for (int g = 0; g < 2; ++g)
                    Oacc[g][d] = __builtin_amdgcn_mfma_f32_16x16x32_bf16(pa[g], vf, Oacc[g][d], 0, 0, 0);
            }
            __builtin_amdgcn_s_setprio(0);
        }
    }

    // epilogue: Lacc[g][r] is already the full row sum (no cross-lane reduce)
    #pragma unroll
    for (int g = 0; g < 2; ++g) {
        int orow = rowQ0 + wq * 32 + g * 16 + quad * 4;
        #pragma unroll
        for (int r = 0; r < 4; ++r) {
            float inv = 1.f / Lacc[g][r];
            #pragma unroll
            for (int d = 0; d < 4; ++d)
                out[(size_t)(orow + r) * D_ + colbase + d * 16 + l15] = Oacc[g][d][r] * inv;
        }
    }
}

extern "C" void kernel_launch(void* const* d_in, const int* in_sizes, int n_in,
                              void* d_out, int out_size, void* d_ws, size_t ws_size,
                              hipStream_t stream) {
    const float* x  = (const float*)d_in[0];
    const float* Wq = (const float*)d_in[1];
    const float* bq = (const float*)d_in[2];
    const float* Wk = (const float*)d_in[3];
    const float* bk = (const float*)d_in[4];
    const float* Wv = (const float*)d_in[5];
    const float* bv = (const float*)d_in[6];
    float* out = (float*)d_out;

    unsigned short* Q   = (unsigned short*)d_ws;
    unsigned short* K   = Q + (size_t)M_ * D_;
    unsigned short* Vtg = K + (size_t)M_ * D_;
    unsigned short* Ax  = Vtg + (size_t)M_ * D_;
    unsigned short* Wtq = Ax + (size_t)M_ * D_;   // Wtq,Wtk,Wtv contiguous [3072][1024]
    unsigned short* Wtk = Wtq + (size_t)D_ * D_;
    unsigned short* Wtv = Wtk + (size_t)D_ * D_;

    cast_fused_kernel<<<8192 + 768, 256, 0, stream>>>(x, Ax, Wq, Wk, Wv, Wtq, Wtk, Wtv);

    gemm_qkv_mfma<<<1536, 256, 0, stream>>>(Ax, Wtq, bq, bk, bv, Q, Vtg);

    attn_mfma<<<1024, 256, 0, stream>>>(Q, K, Vtg, out);
}

// Round 10
// 235.865 us; speedup vs baseline: 1.0187x; 1.0187x over previous
//
#include <hip/hip_runtime.h>

#define B_  4
#define S_  2048
#define D_  1024
#define H_  16
#define DH_ 64
#define M_  (B_ * S_)   // 8192 rows

typedef __attribute__((ext_vector_type(8))) short short8;
typedef __attribute__((ext_vector_type(4))) float floatx4;

// ---------- bf16 helpers ----------
__device__ __forceinline__ unsigned short f2bf(float f) {
    union { float f; unsigned int i; } v; v.f = f;
    unsigned int r = v.i + 0x7fffu + ((v.i >> 16) & 1u);   // RNE
    return (unsigned short)(r >> 16);
}
// truncation pack: two fp32 -> packed bf16x2 (P-weight trunc noise ~3e-5,
// harness-verified). Single v_perm_b32.
__device__ __forceinline__ unsigned int pk_trunc(float a, float b) {
#if __has_builtin(__builtin_amdgcn_perm)
    return __builtin_amdgcn_perm(__float_as_uint(b), __float_as_uint(a), 0x07060302u);
#else
    return (__float_as_uint(a) >> 16) | (__float_as_uint(b) & 0xffff0000u);
#endif
}

// raw 2^x (v_exp_f32). Q pre-scaled by 0.125*log2(e) in the GEMM epilogue.
#if __has_builtin(__builtin_amdgcn_exp2f)
#define EXP2(x) __builtin_amdgcn_exp2f(x)
#else
#define EXP2(x) __expf(0.6931471805599453f * (x))
#endif

// ---------- async global->LDS, 16B per lane ----------
typedef const __attribute__((address_space(1))) unsigned int* gas_ptr;
typedef __attribute__((address_space(3))) unsigned int* las_ptr;
__device__ __forceinline__ void async_cp16(const void* g, void* l) {
    __builtin_amdgcn_global_load_lds((gas_ptr)g, (las_ptr)l, 16, 0, 0);
}

#define VMC4 asm volatile("s_waitcnt vmcnt(4)" ::: "memory")
#define VMC0 asm volatile("s_waitcnt vmcnt(0)" ::: "memory")

// ---------- fused prep: x cast (blocks 0..8191) + W cast-transpose (8192..8959) ----------
__global__ __launch_bounds__(256) void cast_fused_kernel(
    const float* __restrict__ x, unsigned short* __restrict__ Ax,
    const float* __restrict__ W0, const float* __restrict__ W1,
    const float* __restrict__ W2,
    unsigned short* __restrict__ T0, unsigned short* __restrict__ T1,
    unsigned short* __restrict__ T2)
{
    const int bid = blockIdx.x;
    const int t = threadIdx.x;
    if (bid < 8192) {
        int i4 = bid * 256 + t;
        float4 v = reinterpret_cast<const float4*>(x)[i4];
        ushort4 o;
        o.x = f2bf(v.x); o.y = f2bf(v.y); o.z = f2bf(v.z); o.w = f2bf(v.w);
        reinterpret_cast<ushort4*>(Ax)[i4] = o;
        return;
    }
    const int idx = bid - 8192;               // 0..767
    const int z   = idx >> 8;                 // 0..2
    const int rem = idx & 255;
    const float* W = z == 0 ? W0 : (z == 1 ? W1 : W2);
    unsigned short* Wt = z == 0 ? T0 : (z == 1 ? T1 : T2);

    __shared__ unsigned short T[64][72];
    const int k0 = (rem & 15) * 64, n0 = (rem >> 4) * 64;

    #pragma unroll
    for (int p = 0; p < 4; ++p) {
        int kr = p * 16 + (t >> 4);
        int nc = (t & 15) * 4;
        float4 v = *reinterpret_cast<const float4*>(W + (size_t)(k0 + kr) * D_ + n0 + nc);
        T[nc + 0][kr] = f2bf(v.x);
        T[nc + 1][kr] = f2bf(v.y);
        T[nc + 2][kr] = f2bf(v.z);
        T[nc + 3][kr] = f2bf(v.w);
    }
    __syncthreads();

    const int nl = t >> 2, kc = (t & 3) * 16;
    size_t base = (size_t)(n0 + nl) * D_ + k0 + kc;
    *reinterpret_cast<short8*>(Wt + base)     = *reinterpret_cast<const short8*>(&T[nl][kc]);
    *reinterpret_cast<short8*>(Wt + base + 8) = *reinterpret_cast<const short8*>(&T[nl][kc + 8]);
}

// ---------- fused QKV GEMM v3: BM=128 x BN=384, 512 thr, 128KB LDS ----------
// R9 post-mortem: BN=128 doubled A-traffic (FETCH 104->202MB, +16us) and
// 2x256thr blocks = same 8 waves/CU as 1x512 -- no new TLP. Reverted, then
// went the OTHER way: BN=384. Phase-cost accounting across R3/R4/R8 shows
// ~1450-1800cy per phase regardless of contents (barrier+latency dominated),
// so: fewer, fatter phases + less A re-read. Grid 64x8 = 512 = exactly 2
// balanced rounds (vs 3); 64 sequential phases (vs 96); A read 8x = 128MB
// logical (vs 12x/192MB -> FETCH should DROP; if it rises >=150MB the
// theory is wrong). Per phase: af[4] x bfr[6] = 24 MFMA (~233cy/SIMD) vs
// 10 ds_read_b128 (~240cy) -- balanced. LDS 128KB = 2buf x 2Khalf x
// (A 128x32 + B 384x32). Same proven 4-phase counted-vmcnt schedule,
// stage unit now 4 cp16/thread (A 1 + B 3 sweeps) -> VMC4 at P2/P4
// (prologue 12-issue/VMC4; in-flight 4->8->12->drain-8: each wait lands
// exactly the two half-tiles the next two phases read). Same slot-XOR
// zero-conflict layout; B frag offset = (wn*6+j)*512 + fb. XCD map
// g=(id&7)*64+(id>>3) -> nb == xcd: each XCD owns ONE 768KB W-panel,
// L2-resident all launch. BN=384 !| 1024: panels nb=2,5 straddle matrix
// boundaries -> epilogue picks mat per j-fragment (16-col fragments never
// straddle; wave-uniform).
__global__ __launch_bounds__(512, 2) void gemm_qkv_mfma(
    const unsigned short* __restrict__ Ax,
    const unsigned short* __restrict__ Wt,    // [3072][1024] = Q,K,V weights^T
    const float* __restrict__ bq, const float* __restrict__ bk,
    const float* __restrict__ bv,
    unsigned short* __restrict__ Q,           // Q,K contiguous (K = Q + M_*D_)
    unsigned short* __restrict__ Vtg)
{
    __shared__ unsigned short lds[65536];     // 128 KB

    const int tid  = threadIdx.x;             // 0..511
    const int lane = tid & 63;
    const int w    = tid >> 6;                // 0..7
    const int wm   = w >> 2;                  // 0..1  (64-row half of BM=128)
    const int wn   = w & 3;                   // 0..3  (96-col quarter of BN=384)
    const int l15  = lane & 15, quad = lane >> 4;

    // stage constants: lane-linear LDS dest, slot-XOR applied to global source
    const int pl   = tid >> 3;                // 0..63
    const int sl   = tid & 7;
    const int xx   = sl ^ (pl & 7);
    const int sro  = pl * 2 + (xx >> 2);      // logical row 0..127 in sweep
    const int sc   = (xx & 3) * 8;            // k-chunk (shorts)
    // fragment-read offset (same XOR)
    const int fb = (l15 >> 1) * 64 + ((((l15 & 1) << 2) | quad) ^ (l15 >> 1)) * 8;

    const int id  = blockIdx.x;
    const int g   = (id & 7) * 64 + (id >> 3);    // 512 = 8 XCD x 64, bijective
    const int nb  = g >> 6;                   // 0..7  (== XCD id)
    const int mb  = g & 63;                   // 0..63
    const int m0  = mb * 128;
    const int n0g = nb * 384;                 // global col in [0,3072)

    // region bases (shorts): buf0 A0=0 A1=4096 B0=8192 B1=20480; buf1 +32768
    #define ASTG(kcol, reg) \
        async_cp16(Ax + (size_t)(m0 + sro) * 1024 + (kcol) + sc, lds + (reg) + tid * 8)
    #define BSTG(kcol, reg) do { \
        async_cp16(Wt + (size_t)(n0g + sro) * 1024 + (kcol) + sc,       lds + (reg) + tid * 8); \
        async_cp16(Wt + (size_t)(n0g + 128 + sro) * 1024 + (kcol) + sc, lds + (reg) + 4096 + tid * 8); \
        async_cp16(Wt + (size_t)(n0g + 256 + sro) * 1024 + (kcol) + sc, lds + (reg) + 8192 + tid * 8); \
    } while (0)

    floatx4 acc[4][6] = {};

    // prologue: tile0 both halves + tile1 h0 (12 cp16); keep tile1.h0 (4) in flight
    ASTG(0, 0);      BSTG(0, 8192);
    ASTG(32, 4096);  BSTG(32, 20480);
    ASTG(64, 32768); BSTG(64, 40960);
    VMC4;
    __builtin_amdgcn_s_barrier();

    #define PH(bufS, ksub, STAGE_STMT, WAIT_STMT) do { \
        short8 af[4], bfr[6]; \
        _Pragma("unroll") \
        for (int i = 0; i < 4; ++i) \
            af[i] = *reinterpret_cast<const short8*>(lds + (bufS) + (ksub) * 4096 + wm * 2048 + i * 512 + fb); \
        _Pragma("unroll") \
        for (int j = 0; j < 6; ++j) \
            bfr[j] = *reinterpret_cast<const short8*>(lds + (bufS) + 8192 + (ksub) * 12288 + (wn * 6 + j) * 512 + fb); \
        STAGE_STMT; \
        __builtin_amdgcn_s_barrier(); \
        asm volatile("s_waitcnt lgkmcnt(0)" ::: "memory"); \
        __builtin_amdgcn_sched_barrier(0); \
        __builtin_amdgcn_s_setprio(1); \
        _Pragma("unroll") \
        for (int i = 0; i < 4; ++i) \
            _Pragma("unroll") \
            for (int j = 0; j < 6; ++j) \
                acc[i][j] = __builtin_amdgcn_mfma_f32_16x16x32_bf16(af[i], bfr[j], acc[i][j], 0, 0, 0); \
        __builtin_amdgcn_s_setprio(0); \
        WAIT_STMT; \
        __builtin_amdgcn_s_barrier(); \
    } while (0)

    #pragma unroll 1
    for (int it = 0; it < 8; ++it) {
        const bool nl = (it < 7);
        const int  kA = (2 * it + 1) * 64;    // odd tile k-col
        const int  kB = kA + 64;
        const int  kC = kA + 128;
        PH(0,     0, { ASTG(kA + 32, 36864); BSTG(kA + 32, 53248); }, );
        PH(0,     1, if (nl) { ASTG(kB, 0); BSTG(kB, 8192); }, { if (nl) VMC4; else VMC0; });
        PH(32768, 0, if (nl) { ASTG(kB + 32, 4096); BSTG(kB + 32, 20480); }, );
        PH(32768, 1, if (nl) { ASTG(kC, 32768); BSTG(kC, 40960); }, { if (nl) VMC4; });
    }

    // epilogue: per-fragment matrix select (BN=384 straddles 1024-col bounds)
    const int bI    = m0 >> 11;
    const int sbase = (m0 & 2047) + wm * 64;
    #pragma unroll
    for (int j = 0; j < 6; ++j) {
        const int gc0 = n0g + wn * 96 + j * 16;   // fragment base col (16-aligned)
        const int mt  = gc0 >> 10;                // 0=Q 1=K 2=V, wave-uniform
        const int cm  = (gc0 & 1023) + l15;       // col within its matrix
        const float bb = (mt == 0 ? bq : (mt == 1 ? bk : bv))[cm];
        if (mt == 2) {
            #pragma unroll
            for (int i = 0; i < 4; ++i) {
                int srow = sbase + i * 16 + quad * 4;
                ushort4 o;
                o.x = f2bf(acc[i][j][0] + bb);
                o.y = f2bf(acc[i][j][1] + bb);
                o.z = f2bf(acc[i][j][2] + bb);
                o.w = f2bf(acc[i][j][3] + bb);
                *reinterpret_cast<ushort4*>(Vtg + (size_t)(bI * 1024 + cm) * S_ + srow) = o;
            }
        } else {
            unsigned short* C = Q + (size_t)mt * M_ * D_;
            // Q scale folds softmax 1/sqrt(64) AND exp->exp2 log2(e)
            const float scq = (mt == 0) ? 0.18033688011112042f : 1.0f;
            #pragma unroll
            for (int i = 0; i < 4; ++i)
                #pragma unroll
                for (int r = 0; r < 4; ++r) {
                    int row = m0 + wm * 64 + i * 16 + quad * 4 + r;
                    C[(size_t)row * D_ + cm] = f2bf((acc[i][j][r] + bb) * scq);
                }
        }
    }
}

// ---------- MFMA flash attention v10 (R8): conflict-free XOR LDS, kept ----------
// R8 verified: SQ_LDS_BANK_CONFLICT 8.39M -> 0, 71.1us, MfmaUtil 46 + VALU 43
// ~= 89% dual-pipe issue -- structural plateau for this shape.
#define KT_   64
#define NT_   (S_ / KT_)
// logical (row, col in shorts) -> physical short index, conflict-free involution
#define SWZ(row, col) ((((row) << 6)) + ((col) ^ (((row) & 7) << 3)))

__global__ __launch_bounds__(256, 4) void attn_mfma(
    const unsigned short* __restrict__ Qg,
    const unsigned short* __restrict__ Kg,
    const unsigned short* __restrict__ Vtg,   // [(b*16+h)*64+d][s]
    float* __restrict__ out)
{
    __shared__ unsigned short Ks[KT_ * 64];      // [key][d], XOR-swizzled
    __shared__ unsigned short Vt[DH_ * 64];      // [d][k'], key-permuted + XOR-swizzled

    const int tid  = threadIdx.x;
    const int wq   = tid >> 6;
    const int lane = tid & 63;
    const int l15  = lane & 15;
    const int quad = lane >> 4;

    // XCD swizzle: 1024 = 8 xcd x 8 bh x 16 qt; per-XCD K/V footprint 4MB = L2
    const int id  = blockIdx.x;
    const int bh  = (id & 7) * 8 + ((id >> 3) & 7);
    const int qt  = id >> 6;                  // 0..15
    const int b   = bh >> 4;
    const int colbase = (bh & 15) * DH_;
    const int rowQ0 = b * S_ + qt * 128;

    short8 qf[2][2];
    #pragma unroll
    for (int g = 0; g < 2; ++g) {
        int qrow = rowQ0 + wq * 32 + g * 16 + l15;
        qf[g][0] = *reinterpret_cast<const short8*>(Qg + (size_t)qrow * D_ + colbase + quad * 8);
        qf[g][1] = *reinterpret_cast<const short8*>(Qg + (size_t)qrow * D_ + colbase + 32 + quad * 8);
    }

    // all-ones bf16 B-fragment for the denominator MFMA
    short8 vones;
    #pragma unroll
    for (int i = 0; i < 8; ++i) vones[i] = (short)0x3F80;

    floatx4 Oacc[2][4] = {};
    floatx4 Lacc[2] = {};

    // staging: thread covers rows p*32+srow, 16B key-chunk sc8
    const int srow = tid >> 3;        // 0..31
    const int sc8  = (tid & 7) * 8;
    const int vc  = sc8 >> 4;
    const int vqk = (sc8 >> 2) & 3;   // 0 or 2
    const int vk0 = ((vc & 1) << 2) + ((vc >> 1) << 5) + (vqk << 3);

    const unsigned short* Kbase = Kg + (size_t)(b * S_) * D_ + colbase;
    const unsigned short* Vbase = Vtg + (size_t)(bh * 64) * S_;

    short8 kpre[2], vpre[2];
    #pragma unroll
    for (int p = 0; p < 2; ++p) {
        kpre[p] = *reinterpret_cast<const short8*>(Kbase + (size_t)(p * 32 + srow) * D_ + sc8);
        vpre[p] = *reinterpret_cast<const short8*>(Vbase + (size_t)(p * 32 + srow) * S_ + sc8);
    }

    for (int kt = 0; kt < NT_; ++kt) {
        __syncthreads();
        #pragma unroll
        for (int p = 0; p < 2; ++p) {
            int r = p * 32 + srow;
            *reinterpret_cast<short8*>(&Ks[SWZ(r, sc8)]) = kpre[p];
            uint4 u = __builtin_bit_cast(uint4, vpre[p]);
            uint2 lo, hi;
            lo.x = u.x; lo.y = u.y; hi.x = u.z; hi.y = u.w;
            *reinterpret_cast<uint2*>(&Vt[SWZ(r, vk0)])     = lo;
            *reinterpret_cast<uint2*>(&Vt[SWZ(r, vk0 + 8)]) = hi;
        }
        __syncthreads();
        // issue-early: next tile's global loads AFTER the publish barrier
        if (kt + 1 < NT_) {
            int off = (kt + 1) * KT_;
            #pragma unroll
            for (int p = 0; p < 2; ++p) {
                kpre[p] = *reinterpret_cast<const short8*>(Kbase + (size_t)(off + p * 32 + srow) * D_ + sc8);
                vpre[p] = *reinterpret_cast<const short8*>(Vbase + (size_t)(p * 32 + srow) * S_ + off + sc8);
            }
        }

        // process 32 keys (= one PV MFMA's K) per half
        #pragma unroll
        for (int half = 0; half < 2; ++half) {
            floatx4 s_[2][2];
            __builtin_amdgcn_s_setprio(1);
            #pragma unroll
            for (int ci = 0; ci < 2; ++ci) {
                int c = half * 2 + ci;
                int kr = c * 16 + l15;
                short8 kf0 = *reinterpret_cast<const short8*>(&Ks[SWZ(kr, quad * 8)]);
                short8 kf1 = *reinterpret_cast<const short8*>(&Ks[SWZ(kr, 32 + quad * 8)]);
                #pragma unroll
                for (int g = 0; g < 2; ++g) {
                    floatx4 a = {0.f, 0.f, 0.f, 0.f};
                    a = __builtin_amdgcn_mfma_f32_16x16x32_bf16(kf0, qf[g][0], a, 0, 0, 0);
                    a = __builtin_amdgcn_mfma_f32_16x16x32_bf16(kf1, qf[g][1], a, 0, 0, 0);
                    s_[g][ci] = a;
                }
            }
            __builtin_amdgcn_s_setprio(0);
            // exp2 + pack directly into the K=32 A-fragment (k' order)
            short8 pa[2];
            #pragma unroll
            for (int g = 0; g < 2; ++g) {
                float p00 = EXP2(s_[g][0][0]), p01 = EXP2(s_[g][0][1]);
                float p02 = EXP2(s_[g][0][2]), p03 = EXP2(s_[g][0][3]);
                float p10 = EXP2(s_[g][1][0]), p11 = EXP2(s_[g][1][1]);
                float p12 = EXP2(s_[g][1][2]), p13 = EXP2(s_[g][1][3]);
                uint4 pu;
                pu.x = pk_trunc(p00, p01);
                pu.y = pk_trunc(p02, p03);
                pu.z = pk_trunc(p10, p11);
                pu.w = pk_trunc(p12, p13);
                pa[g] = __builtin_bit_cast(short8, pu);
            }
            // denominator + PV on the matrix pipe
            __builtin_amdgcn_s_setprio(1);
            #pragma unroll
            for (int g = 0; g < 2; ++g)
                Lacc[g] = __builtin_amdgcn_mfma_f32_16x16x32_bf16(pa[g], vones, Lacc[g], 0, 0, 0);
            #pragma unroll
            for (int d = 0; d < 4; ++d) {
                int vr = d * 16 + l15;
                short8 vf = *reinterpret_cast<const short8*>(&Vt[SWZ(vr, half * 32 + quad * 8)]);
                #pragma unroll
                for (int g = 0; g < 2; ++g)
                    Oacc[g][d] = __builtin_amdgcn_mfma_f32_16x16x32_bf16(pa[g], vf, Oacc[g][d], 0, 0, 0);
            }
            __builtin_amdgcn_s_setprio(0);
        }
    }

    // epilogue: Lacc[g][r] is already the full row sum (no cross-lane reduce)
    #pragma unroll
    for (int g = 0; g < 2; ++g) {
        int orow = rowQ0 + wq * 32 + g * 16 + quad * 4;
        #pragma unroll
        for (int r = 0; r < 4; ++r) {
            float inv = 1.f / Lacc[g][r];
            #pragma unroll
            for (int d = 0; d < 4; ++d)
                out[(size_t)(orow + r) * D_ + colbase + d * 16 + l15] = Oacc[g][d][r] * inv;
        }
    }
}

extern "C" void kernel_launch(void* const* d_in, const int* in_sizes, int n_in,
                              void* d_out, int out_size, void* d_ws, size_t ws_size,
                              hipStream_t stream) {
    const float* x  = (const float*)d_in[0];
    const float* Wq = (const float*)d_in[1];
    const float* bq = (const float*)d_in[2];
    const float* Wk = (const float*)d_in[3];
    const float* bk = (const float*)d_in[4];
    const float* Wv = (const float*)d_in[5];
    const float* bv = (const float*)d_in[6];
    float* out = (float*)d_out;

    unsigned short* Q   = (unsigned short*)d_ws;
    unsigned short* K   = Q + (size_t)M_ * D_;
    unsigned short* Vtg = K + (size_t)M_ * D_;
    unsigned short* Ax  = Vtg + (size_t)M_ * D_;
    unsigned short* Wtq = Ax + (size_t)M_ * D_;   // Wtq,Wtk,Wtv contiguous [3072][1024]
    unsigned short* Wtk = Wtq + (size_t)D_ * D_;
    unsigned short* Wtv = Wtk + (size_t)D_ * D_;

    cast_fused_kernel<<<8192 + 768, 256, 0, stream>>>(x, Ax, Wq, Wk, Wv, Wtq, Wtk, Wtv);

    gemm_qkv_mfma<<<512, 512, 0, stream>>>(Ax, Wtq, bq, bk, bv, Q, Vtg);

    attn_mfma<<<1024, 256, 0, stream>>>(Q, K, Vtg, out);
}

// Round 11
// 228.790 us; speedup vs baseline: 1.0502x; 1.0309x over previous
//
#include <hip/hip_runtime.h>

#define B_  4
#define S_  2048
#define D_  1024
#define H_  16
#define DH_ 64
#define M_  (B_ * S_)   // 8192 rows

typedef __attribute__((ext_vector_type(8))) short short8;
typedef __attribute__((ext_vector_type(4))) float floatx4;

// ---------- bf16 helpers ----------
__device__ __forceinline__ unsigned short f2bf(float f) {
    union { float f; unsigned int i; } v; v.f = f;
    unsigned int r = v.i + 0x7fffu + ((v.i >> 16) & 1u);   // RNE
    return (unsigned short)(r >> 16);
}
// truncation pack: two fp32 -> packed bf16x2 (P-weight trunc noise ~3e-5,
// harness-verified). Single v_perm_b32.
__device__ __forceinline__ unsigned int pk_trunc(float a, float b) {
#if __has_builtin(__builtin_amdgcn_perm)
    return __builtin_amdgcn_perm(__float_as_uint(b), __float_as_uint(a), 0x07060302u);
#else
    return (__float_as_uint(a) >> 16) | (__float_as_uint(b) & 0xffff0000u);
#endif
}

// raw 2^x (v_exp_f32). Q pre-scaled by 0.125*log2(e) in the GEMM epilogue.
#if __has_builtin(__builtin_amdgcn_exp2f)
#define EXP2(x) __builtin_amdgcn_exp2f(x)
#else
#define EXP2(x) __expf(0.6931471805599453f * (x))
#endif

// ---------- async global->LDS, 16B per lane ----------
typedef const __attribute__((address_space(1))) unsigned int* gas_ptr;
typedef __attribute__((address_space(3))) unsigned int* las_ptr;
__device__ __forceinline__ void async_cp16(const void* g, void* l) {
    __builtin_amdgcn_global_load_lds((gas_ptr)g, (las_ptr)l, 16, 0, 0);
}

#define VMC4 asm volatile("s_waitcnt vmcnt(4)" ::: "memory")
#define VMC0 asm volatile("s_waitcnt vmcnt(0)" ::: "memory")

// ---------- fused prep: x cast (blocks 0..8191) + W cast-transpose (8192..8959) ----------
__global__ __launch_bounds__(256) void cast_fused_kernel(
    const float* __restrict__ x, unsigned short* __restrict__ Ax,
    const float* __restrict__ W0, const float* __restrict__ W1,
    const float* __restrict__ W2,
    unsigned short* __restrict__ T0, unsigned short* __restrict__ T1,
    unsigned short* __restrict__ T2)
{
    const int bid = blockIdx.x;
    const int t = threadIdx.x;
    if (bid < 8192) {
        int i4 = bid * 256 + t;
        float4 v = reinterpret_cast<const float4*>(x)[i4];
        ushort4 o;
        o.x = f2bf(v.x); o.y = f2bf(v.y); o.z = f2bf(v.z); o.w = f2bf(v.w);
        reinterpret_cast<ushort4*>(Ax)[i4] = o;
        return;
    }
    const int idx = bid - 8192;               // 0..767
    const int z   = idx >> 8;                 // 0..2
    const int rem = idx & 255;
    const float* W = z == 0 ? W0 : (z == 1 ? W1 : W2);
    unsigned short* Wt = z == 0 ? T0 : (z == 1 ? T1 : T2);

    __shared__ unsigned short T[64][72];
    const int k0 = (rem & 15) * 64, n0 = (rem >> 4) * 64;

    #pragma unroll
    for (int p = 0; p < 4; ++p) {
        int kr = p * 16 + (t >> 4);
        int nc = (t & 15) * 4;
        float4 v = *reinterpret_cast<const float4*>(W + (size_t)(k0 + kr) * D_ + n0 + nc);
        T[nc + 0][kr] = f2bf(v.x);
        T[nc + 1][kr] = f2bf(v.y);
        T[nc + 2][kr] = f2bf(v.z);
        T[nc + 3][kr] = f2bf(v.w);
    }
    __syncthreads();

    const int nl = t >> 2, kc = (t & 3) * 16;
    size_t base = (size_t)(n0 + nl) * D_ + k0 + kc;
    *reinterpret_cast<short8*>(Wt + base)     = *reinterpret_cast<const short8*>(&T[nl][kc]);
    *reinterpret_cast<short8*>(Wt + base + 8) = *reinterpret_cast<const short8*>(&T[nl][kc + 8]);
}

// ---------- fused QKV GEMM v3 (R10): BM=128 x BN=384, 512 thr, 128KB LDS ----------
// R10 verified: gemm dropped below attn (<73us, from 82.0/71.5). Kept as-is.
__global__ __launch_bounds__(512, 2) void gemm_qkv_mfma(
    const unsigned short* __restrict__ Ax,
    const unsigned short* __restrict__ Wt,    // [3072][1024] = Q,K,V weights^T
    const float* __restrict__ bq, const float* __restrict__ bk,
    const float* __restrict__ bv,
    unsigned short* __restrict__ Q,           // Q,K contiguous (K = Q + M_*D_)
    unsigned short* __restrict__ Vtg)
{
    __shared__ unsigned short lds[65536];     // 128 KB

    const int tid  = threadIdx.x;             // 0..511
    const int lane = tid & 63;
    const int w    = tid >> 6;                // 0..7
    const int wm   = w >> 2;                  // 0..1  (64-row half of BM=128)
    const int wn   = w & 3;                   // 0..3  (96-col quarter of BN=384)
    const int l15  = lane & 15, quad = lane >> 4;

    // stage constants: lane-linear LDS dest, slot-XOR applied to global source
    const int pl   = tid >> 3;                // 0..63
    const int sl   = tid & 7;
    const int xx   = sl ^ (pl & 7);
    const int sro  = pl * 2 + (xx >> 2);      // logical row 0..127 in sweep
    const int sc   = (xx & 3) * 8;            // k-chunk (shorts)
    // fragment-read offset (same XOR)
    const int fb = (l15 >> 1) * 64 + ((((l15 & 1) << 2) | quad) ^ (l15 >> 1)) * 8;

    const int id  = blockIdx.x;
    const int g   = (id & 7) * 64 + (id >> 3);    // 512 = 8 XCD x 64, bijective
    const int nb  = g >> 6;                   // 0..7  (== XCD id)
    const int mb  = g & 63;                   // 0..63
    const int m0  = mb * 128;
    const int n0g = nb * 384;                 // global col in [0,3072)

    // region bases (shorts): buf0 A0=0 A1=4096 B0=8192 B1=20480; buf1 +32768
    #define ASTG(kcol, reg) \
        async_cp16(Ax + (size_t)(m0 + sro) * 1024 + (kcol) + sc, lds + (reg) + tid * 8)
    #define BSTG(kcol, reg) do { \
        async_cp16(Wt + (size_t)(n0g + sro) * 1024 + (kcol) + sc,       lds + (reg) + tid * 8); \
        async_cp16(Wt + (size_t)(n0g + 128 + sro) * 1024 + (kcol) + sc, lds + (reg) + 4096 + tid * 8); \
        async_cp16(Wt + (size_t)(n0g + 256 + sro) * 1024 + (kcol) + sc, lds + (reg) + 8192 + tid * 8); \
    } while (0)

    floatx4 acc[4][6] = {};

    // prologue: tile0 both halves + tile1 h0 (12 cp16); keep tile1.h0 (4) in flight
    ASTG(0, 0);      BSTG(0, 8192);
    ASTG(32, 4096);  BSTG(32, 20480);
    ASTG(64, 32768); BSTG(64, 40960);
    VMC4;
    __builtin_amdgcn_s_barrier();

    #define PH(bufS, ksub, STAGE_STMT, WAIT_STMT) do { \
        short8 af[4], bfr[6]; \
        _Pragma("unroll") \
        for (int i = 0; i < 4; ++i) \
            af[i] = *reinterpret_cast<const short8*>(lds + (bufS) + (ksub) * 4096 + wm * 2048 + i * 512 + fb); \
        _Pragma("unroll") \
        for (int j = 0; j < 6; ++j) \
            bfr[j] = *reinterpret_cast<const short8*>(lds + (bufS) + 8192 + (ksub) * 12288 + (wn * 6 + j) * 512 + fb); \
        STAGE_STMT; \
        __builtin_amdgcn_s_barrier(); \
        asm volatile("s_waitcnt lgkmcnt(0)" ::: "memory"); \
        __builtin_amdgcn_sched_barrier(0); \
        __builtin_amdgcn_s_setprio(1); \
        _Pragma("unroll") \
        for (int i = 0; i < 4; ++i) \
            _Pragma("unroll") \
            for (int j = 0; j < 6; ++j) \
                acc[i][j] = __builtin_amdgcn_mfma_f32_16x16x32_bf16(af[i], bfr[j], acc[i][j], 0, 0, 0); \
        __builtin_amdgcn_s_setprio(0); \
        WAIT_STMT; \
        __builtin_amdgcn_s_barrier(); \
    } while (0)

    #pragma unroll 1
    for (int it = 0; it < 8; ++it) {
        const bool nl = (it < 7);
        const int  kA = (2 * it + 1) * 64;    // odd tile k-col
        const int  kB = kA + 64;
        const int  kC = kA + 128;
        PH(0,     0, { ASTG(kA + 32, 36864); BSTG(kA + 32, 53248); }, );
        PH(0,     1, if (nl) { ASTG(kB, 0); BSTG(kB, 8192); }, { if (nl) VMC4; else VMC0; });
        PH(32768, 0, if (nl) { ASTG(kB + 32, 4096); BSTG(kB + 32, 20480); }, );
        PH(32768, 1, if (nl) { ASTG(kC, 32768); BSTG(kC, 40960); }, { if (nl) VMC4; });
    }

    // epilogue: per-fragment matrix select (BN=384 straddles 1024-col bounds)
    const int bI    = m0 >> 11;
    const int sbase = (m0 & 2047) + wm * 64;
    #pragma unroll
    for (int j = 0; j < 6; ++j) {
        const int gc0 = n0g + wn * 96 + j * 16;   // fragment base col (16-aligned)
        const int mt  = gc0 >> 10;                // 0=Q 1=K 2=V, wave-uniform
        const int cm  = (gc0 & 1023) + l15;       // col within its matrix
        const float bb = (mt == 0 ? bq : (mt == 1 ? bk : bv))[cm];
        if (mt == 2) {
            #pragma unroll
            for (int i = 0; i < 4; ++i) {
                int srow = sbase + i * 16 + quad * 4;
                ushort4 o;
                o.x = f2bf(acc[i][j][0] + bb);
                o.y = f2bf(acc[i][j][1] + bb);
                o.z = f2bf(acc[i][j][2] + bb);
                o.w = f2bf(acc[i][j][3] + bb);
                *reinterpret_cast<ushort4*>(Vtg + (size_t)(bI * 1024 + cm) * S_ + srow) = o;
            }
        } else {
            unsigned short* C = Q + (size_t)mt * M_ * D_;
            // Q scale folds softmax 1/sqrt(64) AND exp->exp2 log2(e)
            const float scq = (mt == 0) ? 0.18033688011112042f : 1.0f;
            #pragma unroll
            for (int i = 0; i < 4; ++i)
                #pragma unroll
                for (int r = 0; r < 4; ++r) {
                    int row = m0 + wm * 64 + i * 16 + quad * 4 + r;
                    C[(size_t)row * D_ + cm] = f2bf((acc[i][j][r] + bb) * scq);
                }
        }
    }
}

// ---------- MFMA flash attention v11: KT=128 -- half the barrier rendezvous ----------
// R10 counters: MfmaUtil 45.9 + VALUBusy 42.9 ~= 89% dual-pipe issue,
// conflicts 0. Residual ~11% = per-tile rendezvous (2 barriers + publish per
// 64 keys x 32 tiles). Both pipes balanced -> only amortization is left:
// KT 64->128. LDS 16->32KB (4 blocks/CU = 128KB, fits); barrier pairs 32->16;
// +16 VGPR prefetch (~72 total, under the 128 cap). k' permutation extends
// verbatim: global k' = q*64 + k'_64 aligns exactly with PV's half*32+quad*8
// for half 0..3 (A-side key(kk) = half*32+(j>=4)*16+quad*4+(j&3), derived).
// SWZ splits into SWZK (64-col rows) / SWZV (128-col rows); XOR touches only
// col bits 3-5 so conflict-freedom carries over per 64-col group.
#define KT_   128
#define NT_   (S_ / KT_)
#define SWZK(row, col) (((row) << 6) + ((col) ^ (((row) & 7) << 3)))
#define SWZV(row, col) (((row) << 7) + ((col) ^ (((row) & 7) << 3)))

__global__ __launch_bounds__(256, 4) void attn_mfma(
    const unsigned short* __restrict__ Qg,
    const unsigned short* __restrict__ Kg,
    const unsigned short* __restrict__ Vtg,   // [(b*16+h)*64+d][s]
    float* __restrict__ out)
{
    __shared__ unsigned short Ks[KT_ * 64];      // [key][d], XOR-swizzled     (16 KB)
    __shared__ unsigned short Vt[DH_ * 128];     // [d][k'], permuted+swizzled (16 KB)

    const int tid  = threadIdx.x;
    const int wq   = tid >> 6;
    const int lane = tid & 63;
    const int l15  = lane & 15;
    const int quad = lane >> 4;

    // XCD swizzle: 1024 = 8 xcd x 8 bh x 16 qt; per-XCD K/V footprint 4MB = L2
    const int id  = blockIdx.x;
    const int bh  = (id & 7) * 8 + ((id >> 3) & 7);
    const int qt  = id >> 6;                  // 0..15
    const int b   = bh >> 4;
    const int colbase = (bh & 15) * DH_;
    const int rowQ0 = b * S_ + qt * 128;

    short8 qf[2][2];
    #pragma unroll
    for (int g = 0; g < 2; ++g) {
        int qrow = rowQ0 + wq * 32 + g * 16 + l15;
        qf[g][0] = *reinterpret_cast<const short8*>(Qg + (size_t)qrow * D_ + colbase + quad * 8);
        qf[g][1] = *reinterpret_cast<const short8*>(Qg + (size_t)qrow * D_ + colbase + 32 + quad * 8);
    }

    // all-ones bf16 B-fragment for the denominator MFMA
    short8 vones;
    #pragma unroll
    for (int i = 0; i < 8; ++i) vones[i] = (short)0x3F80;

    floatx4 Oacc[2][4] = {};
    floatx4 Lacc[2] = {};

    // staging: thread covers rows p*32+srow, 16B key-chunk sc8
    const int srow = tid >> 3;        // 0..31
    const int sc8  = (tid & 7) * 8;
    const int vc  = sc8 >> 4;
    const int vqk = (sc8 >> 2) & 3;   // 0 or 2
    const int vk0 = ((vc & 1) << 2) + ((vc >> 1) << 5) + (vqk << 3);

    const unsigned short* Kbase = Kg + (size_t)(b * S_) * D_ + colbase;
    const unsigned short* Vbase = Vtg + (size_t)(bh * 64) * S_;

    short8 kpre[4], vpre[2][2];
    #pragma unroll
    for (int p = 0; p < 4; ++p)
        kpre[p] = *reinterpret_cast<const short8*>(Kbase + (size_t)(p * 32 + srow) * D_ + sc8);
    #pragma unroll
    for (int p = 0; p < 2; ++p)
        #pragma unroll
        for (int q = 0; q < 2; ++q)
            vpre[p][q] = *reinterpret_cast<const short8*>(Vbase + (size_t)(p * 32 + srow) * S_ + q * 64 + sc8);

    for (int kt = 0; kt < NT_; ++kt) {
        __syncthreads();
        #pragma unroll
        for (int p = 0; p < 4; ++p)
            *reinterpret_cast<short8*>(&Ks[SWZK(p * 32 + srow, sc8)]) = kpre[p];
        #pragma unroll
        for (int p = 0; p < 2; ++p)
            #pragma unroll
            for (int q = 0; q < 2; ++q) {
                int r = p * 32 + srow;
                uint4 u = __builtin_bit_cast(uint4, vpre[p][q]);
                uint2 lo, hi;
                lo.x = u.x; lo.y = u.y; hi.x = u.z; hi.y = u.w;
                *reinterpret_cast<uint2*>(&Vt[SWZV(r, q * 64 + vk0)])     = lo;
                *reinterpret_cast<uint2*>(&Vt[SWZV(r, q * 64 + vk0 + 8)]) = hi;
            }
        __syncthreads();
        // issue-early: next tile's global loads AFTER the publish barrier;
        // they complete under this tile's ~2x compute.
        if (kt + 1 < NT_) {
            int off = (kt + 1) * KT_;
            #pragma unroll
            for (int p = 0; p < 4; ++p)
                kpre[p] = *reinterpret_cast<const short8*>(Kbase + (size_t)(off + p * 32 + srow) * D_ + sc8);
            #pragma unroll
            for (int p = 0; p < 2; ++p)
                #pragma unroll
                for (int q = 0; q < 2; ++q)
                    vpre[p][q] = *reinterpret_cast<const short8*>(Vbase + (size_t)(p * 32 + srow) * S_ + off + q * 64 + sc8);
        }

        // process 32 keys (= one PV MFMA's K) per half; 4 halves per tile
        #pragma unroll
        for (int half = 0; half < 4; ++half) {
            floatx4 s_[2][2];
            __builtin_amdgcn_s_setprio(1);
            #pragma unroll
            for (int ci = 0; ci < 2; ++ci) {
                int kr = (half * 2 + ci) * 16 + l15;
                short8 kf0 = *reinterpret_cast<const short8*>(&Ks[SWZK(kr, quad * 8)]);
                short8 kf1 = *reinterpret_cast<const short8*>(&Ks[SWZK(kr, 32 + quad * 8)]);
                #pragma unroll
                for (int g = 0; g < 2; ++g) {
                    floatx4 a = {0.f, 0.f, 0.f, 0.f};
                    a = __builtin_amdgcn_mfma_f32_16x16x32_bf16(kf0, qf[g][0], a, 0, 0, 0);
                    a = __builtin_amdgcn_mfma_f32_16x16x32_bf16(kf1, qf[g][1], a, 0, 0, 0);
                    s_[g][ci] = a;
                }
            }
            __builtin_amdgcn_s_setprio(0);
            // exp2 + pack directly into the K=32 A-fragment (k' order)
            short8 pa[2];
            #pragma unroll
            for (int g = 0; g < 2; ++g) {
                float p00 = EXP2(s_[g][0][0]), p01 = EXP2(s_[g][0][1]);
                float p02 = EXP2(s_[g][0][2]), p03 = EXP2(s_[g][0][3]);
                float p10 = EXP2(s_[g][1][0]), p11 = EXP2(s_[g][1][1]);
                float p12 = EXP2(s_[g][1][2]), p13 = EXP2(s_[g][1][3]);
                uint4 pu;
                pu.x = pk_trunc(p00, p01);
                pu.y = pk_trunc(p02, p03);
                pu.z = pk_trunc(p10, p11);
                pu.w = pk_trunc(p12, p13);
                pa[g] = __builtin_bit_cast(short8, pu);
            }
            // denominator + PV on the matrix pipe
            __builtin_amdgcn_s_setprio(1);
            #pragma unroll
            for (int g = 0; g < 2; ++g)
                Lacc[g] = __builtin_amdgcn_mfma_f32_16x16x32_bf16(pa[g], vones, Lacc[g], 0, 0, 0);
            #pragma unroll
            for (int d = 0; d < 4; ++d) {
                short8 vf = *reinterpret_cast<const short8*>(
                    &Vt[SWZV(d * 16 + l15, half * 32 + quad * 8)]);
                #pragma unroll
                for (int g = 0; g < 2; ++g)
                    Oacc[g][d] = __builtin_amdgcn_mfma_f32_16x16x32_bf16(pa[g], vf, Oacc[g][d], 0, 0, 0);
            }
            __builtin_amdgcn_s_setprio(0);
        }
    }

    // epilogue: Lacc[g][r] is already the full row sum (no cross-lane reduce)
    #pragma unroll
    for (int g = 0; g < 2; ++g) {
        int orow = rowQ0 + wq * 32 + g * 16 + quad * 4;
        #pragma unroll
        for (int r = 0; r < 4; ++r) {
            float inv = 1.f / Lacc[g][r];
            #pragma unroll
            for (int d = 0; d < 4; ++d)
                out[(size_t)(orow + r) * D_ + colbase + d * 16 + l15] = Oacc[g][d][r] * inv;
        }
    }
}

extern "C" void kernel_launch(void* const* d_in, const int* in_sizes, int n_in,
                              void* d_out, int out_size, void* d_ws, size_t ws_size,
                              hipStream_t stream) {
    const float* x  = (const float*)d_in[0];
    const float* Wq = (const float*)d_in[1];
    const float* bq = (const float*)d_in[2];
    const float* Wk = (const float*)d_in[3];
    const float* bk = (const float*)d_in[4];
    const float* Wv = (const float*)d_in[5];
    const float* bv = (const float*)d_in[6];
    float* out = (float*)d_out;

    unsigned short* Q   = (unsigned short*)d_ws;
    unsigned short* K   = Q + (size_t)M_ * D_;
    unsigned short* Vtg = K + (size_t)M_ * D_;
    unsigned short* Ax  = Vtg + (size_t)M_ * D_;
    unsigned short* Wtq = Ax + (size_t)M_ * D_;   // Wtq,Wtk,Wtv contiguous [3072][1024]
    unsigned short* Wtk = Wtq + (size_t)D_ * D_;
    unsigned short* Wtv = Wtk + (size_t)D_ * D_;

    cast_fused_kernel<<<8192 + 768, 256, 0, stream>>>(x, Ax, Wq, Wk, Wv, Wtq, Wtk, Wtv);

    gemm_qkv_mfma<<<512, 512, 0, stream>>>(Ax, Wtq, bq, bk, bv, Q, Vtg);

    attn_mfma<<<1024, 256, 0, stream>>>(Q, K, Vtg, out);
}